// Round 15
// baseline (127.003 us; speedup 1.0000x reference)
//
#include <hip/hip_runtime.h>
#include <stdint.h>

// out[n,o] = sum_{d,i} q[n,d] x[n,i] W1[d,i,o] + (q @ b1)[n,o]
// GEMM M=4096 N=256 K=16384 (k = d*256 + i), fp16 MFMA 32x32x16, fp32 accum.
//
// ROUND 15 = ROUND 14 with the compile fix: __builtin_amdgcn_s_waitcnt needs
// a LITERAL constant -> branch on unrolled s, constant in each arm.
// Theory unchanged (T4 counted-vmcnt, m218): tri-buffer sw[3], stage step
// s+2 AFTER barrier(s) (race-free: barrier(s) => all waves done with step
// s-1 whose buffer s+2 overwrites), per-step {vmcnt(2); s_barrier;
// STAGE(s+2); setprio(1); CSTEP; setprio(0)} -> 2 loads/wave stay in flight
// across every barrier; only step 15 waits vmcnt(0). sched_barrier(0) fences
// ds_read hoisting (rule 18).
// Geometry (R9, verified): tile M=256 x N=64, ksplit=8 over d, grid 512 =
// 16 mb x 4 nc x 8 ks; 8 waves = 4m x 2n, wave = 64 rows x 32 cols; W staged
// 16 KB/step, x/q in registers; fp32 stripes x8 + reduce8; bias in ks==0.
// prep = R13's (banked: one wave per 1KB chunk, coalesced both sides).

typedef _Float16 f16;
typedef f16 f16x8 __attribute__((ext_vector_type(8)));
typedef float f32x16 __attribute__((ext_vector_type(16)));

#define QDIM 64

__device__ __forceinline__ void gl_lds16(const void* g, void* s) {
  __builtin_amdgcn_global_load_lds(
      (const __attribute__((address_space(1))) void*)(uintptr_t)g,
      (__attribute__((address_space(3))) void*)(uint32_t)(uintptr_t)s,
      16, 0, 0);
}

// one fp32-float8 -> f16x8
#define XFRAG(DST, PTR)                                      \
  do {                                                       \
    float4 a_ = *(const float4*)(PTR);                       \
    float4 b_ = *(const float4*)((PTR) + 4);                 \
    f16x8 h_;                                                \
    h_[0] = (f16)a_.x; h_[1] = (f16)a_.y; h_[2] = (f16)a_.z; \
    h_[3] = (f16)a_.w; h_[4] = (f16)b_.x; h_[5] = (f16)b_.y; \
    h_[6] = (f16)b_.z; h_[7] = (f16)b_.w;                    \
    DST = h_;                                                \
  } while (0)

// ---------------- prep (R13's banked version — verified) ----------------
// Wt layout (8 MB):  byte = ((ncg*64 + d)*16 + ic)*1024 + hf*512 + c*16 + j*2
//   <- W1[d][ic*16 + hf*8 + j][ncg*32 + c]   (B-frag lane-linear, 1KB chunks)
// Xt layout (2 MB):  byte = ((t64*16 + ic)*2 + hf)*1024 + row*16 + j*2
//   <- x[t64*64 + row][ic*16 + hf*8 + j]     (A-frag lane-linear, 64-row tiles)
// Bt layout (32 KB): byte = ((ncg*4 + kc)*2 + hf)*512 + c*16 + j*2
//   <- b1[kc*16 + hf*8 + j][ncg*32 + c]
// grid 2113: [0,2048) W (1 chunk/wave) | [2048,2112) Xt | 2112 Bt
__global__ __launch_bounds__(256) void prep(const float* __restrict__ W,
                                            const float* __restrict__ B1,
                                            const float* __restrict__ X,
                                            f16* __restrict__ Wt,
                                            f16* __restrict__ Xt,
                                            f16* __restrict__ Bt) {
  const int b = blockIdx.x, t = threadIdx.x;
  if (b < 2048) {
    const int w = t >> 6, l = t & 63, hf = l >> 5, c = l & 31;
    const int g = (b << 2) + w;   // chunk id 0..8191 = (ncg*64 + d)*16 + ic
    const int ic = g & 15;
    const int d = (g >> 4) & 63;
    const int ncg = g >> 10;
    const float* src = W + ((size_t)(d * 256 + (ic << 4) + (hf << 3)) << 8) +
                       (ncg << 5) + c;
    f16x8 h;
#pragma unroll
    for (int j = 0; j < 8; ++j) h[j] = (f16)src[(size_t)j << 8];
    *(f16x8*)((char*)Wt + ((size_t)g << 10) + (hf << 9) + (c << 4)) = h;
  } else if (b < 2112) {
    const int mb = b - 2048;  // 64-row tiles
#pragma unroll
    for (int rep = 0; rep < 8; ++rep) {
      const int u = (rep << 8) + t;          // 0..2047
      const int row = u & 63, ish = u >> 6;  // i = ish*8 + j
      const float* src = X + ((size_t)((mb << 6) + row)) * 256 + (ish << 3);
      f16x8 h;
      XFRAG(h, src);
      *(f16x8*)((char*)Xt + ((((size_t)mb * 16 + (ish >> 1)) * 2 + (ish & 1)) << 10) +
                (row << 4)) = h;
    }
  } else {
#pragma unroll
    for (int kb = 0; kb < 8; ++kb) {  // k = kb*8 + j
      const float* src = B1 + ((size_t)kb << 3) * 256 + t;
      f16x8 h;
#pragma unroll
      for (int j = 0; j < 8; ++j) h[j] = (f16)src[(size_t)j << 8];
      *(f16x8*)((char*)Bt + (((size_t)(t >> 5) * 4 + (kb >> 1)) << 10) +
                ((kb & 1) << 9) + ((t & 31) << 4)) = h;
    }
  }
}

// ---- main: 512 blocks = 16 mb (256 rows) x 4 nc (64 cols) x 8 ks (8 d's) ----
// 8 waves = 4m x 2n; wave = 64 rows x 32 cols (2 m-subtiles).
__global__ __launch_bounds__(512, 2) void mlp_main(const float* __restrict__ Q,
                                                   const f16* __restrict__ Wt,
                                                   const f16* __restrict__ Xt,
                                                   const f16* __restrict__ Bt,
                                                   float* __restrict__ P) {
  __shared__ __align__(16) char sw[3][16384];  // tri-buffer, 48 KB

  const int bid = blockIdx.x;
  const int nc = bid & 3;          // 64-col tile
  const int ks = (bid >> 2) & 7;   // d-range [ks*8, ks*8+8)
  const int mb = bid >> 5;         // 0..15, 256-row tile
  const int t = threadIdx.x;
  const int w = t >> 6;            // 0..7
  const int wn = w & 1;            // n-subtile (32 cols)
  const int wm = w >> 1;           // 0..3 (64-row slice)
  const int l = t & 63;
  const int l31 = l & 31;
  const int hf = l >> 5;

  const int dlo = ks << 3;
  const int st = mb & 7;  // d-walk stagger across same-slice blocks

  // global W base for this nc: chunk(ncg=nc*2+nsub, d, icAbs) at
  // + (nsub<<20) + (d<<14) + (icAbs<<10); lane adds l*16.
  const char* gW = (const char*)(Wt) + ((size_t)nc << 21) + (l << 4);

  // x-frag base: tile64 = mb*4 + wm; frag(icAbs, msub) at +(icAbs<<11)+(msub<<9)
  const char* xB = (const char*)Xt + ((size_t)((mb << 2) + wm) << 15) +
                   (hf << 10) + (l31 << 4);

  // q scalars, rotated: qr{0,1}[dt] = q[row_msub][dlo + (dt+st)&7]
  f16 qr0[8], qr1[8];
  {
    const float* qp0 = Q + ((size_t)((mb << 8) + (wm << 6) + l31)) * QDIM + dlo;
    const float* qp1 = qp0 + (size_t)32 * QDIM;
#pragma unroll
    for (int dt = 0; dt < 8; ++dt) {
      qr0[dt] = (f16)qp0[(dt + st) & 7];
      qr1[dt] = (f16)qp1[(dt + st) & 7];
    }
  }

  f32x16 acc0, acc1;
#pragma unroll
  for (int r = 0; r < 16; ++r) { acc0[r] = 0.f; acc1[r] = 0.f; }

  f16x8 xf[16];  // [k2*2 + msub] for current i-half

// stage one step's 16 chunks: wave w stages ic-sub w (2 nsub chunks)
#define STAGE2(H, DABS, SBUF)                                              \
  do {                                                                     \
    gl_lds16(gW + ((size_t)(DABS) << 14) + ((((H) << 3) + w) << 10),       \
             (SBUF) + ((w << 1) << 10) + (l << 4));                        \
    gl_lds16(gW + ((size_t)1 << 20) + ((size_t)(DABS) << 14) +             \
                 ((((H) << 3) + w) << 10),                                 \
             (SBUF) + (((w << 1) + 1) << 10) + (l << 4));                  \
  } while (0)

#define LOADXF(H)                                                          \
  do {                                                                     \
    _Pragma("unroll")                                                      \
    for (int k2 = 0; k2 < 8; ++k2) {                                       \
      xf[k2 * 2 + 0] = *(const f16x8*)(xB + ((((H) << 3) + k2) << 11));    \
      xf[k2 * 2 + 1] =                                                     \
          *(const f16x8*)(xB + ((((H) << 3) + k2) << 11) + (1 << 9));      \
    }                                                                      \
  } while (0)

// consume one step from SBUF (d-index dt): 8 ds_read + 16 MFMA
#define CSTEP(DT, SBUF)                                                    \
  do {                                                                     \
    const f16 qa_ = qr0[DT], qb_ = qr1[DT];                                \
    _Pragma("unroll")                                                      \
    for (int k2 = 0; k2 < 8; ++k2) {                                       \
      f16x8 bf_ = *(const f16x8*)((SBUF) + (((k2 << 1) | wn) << 10) +      \
                                  (l << 4));                               \
      acc0 = __builtin_amdgcn_mfma_f32_32x32x16_f16(xf[k2 * 2 + 0] * qa_,  \
                                                    bf_, acc0, 0, 0, 0);   \
      acc1 = __builtin_amdgcn_mfma_f32_32x32x16_f16(xf[k2 * 2 + 1] * qb_,  \
                                                    bf_, acc1, 0, 0, 0);   \
    }                                                                      \
  } while (0)

  // prologue: x half 0, stage steps 0 and 1 into sw[0], sw[1]
  LOADXF(0);
  STAGE2(0, dlo + ((0 + st) & 7), (char*)sw[0]);
  STAGE2(0, dlo + ((1 + st) & 7), (char*)sw[1]);

  // 16 steps = (h 0..1) x (dt 0..7); step s consumes sw[s%3] (staged at s-2),
  // stages step s+2 into sw[(s+2)%3]. vmcnt(2) keeps next step's stage in
  // flight across the barrier; only s=15 (nothing newer) waits vmcnt(0).
#pragma unroll
  for (int h = 0; h < 2; ++h) {
#pragma unroll
    for (int dt = 0; dt < 8; ++dt) {
      const int s = (h << 3) + dt;
      if (s == 15) {
        __builtin_amdgcn_s_waitcnt(0x0F70);  // vmcnt(0)
      } else {
        __builtin_amdgcn_s_waitcnt(0x0F72);  // vmcnt(2)
      }
      __builtin_amdgcn_sched_barrier(0);
      __builtin_amdgcn_s_barrier();
      __builtin_amdgcn_sched_barrier(0);
      if (s < 14) {
        const int s2 = s + 2, hn = s2 >> 3, dtn = s2 & 7;
        char* nb = (char*)sw[s2 % 3];
        STAGE2(hn, dlo + ((dtn + st) & 7), nb);
      }
      __builtin_amdgcn_s_setprio(1);
      CSTEP(dt, (const char*)sw[s % 3]);
      __builtin_amdgcn_s_setprio(0);
      if (s == 7) LOADXF(1);  // x half 1 (after last h0 use)
    }
  }

  // bias (ks==0 blocks): 4 chunks over QDIM, A = q-frag, B = Bt (global reads)
  if (ks == 0) {
    const int ncg = (nc << 1) + wn;
#pragma unroll
    for (int kc = 0; kc < 4; ++kc) {
      f16x8 bf = *(const f16x8*)((const char*)Bt +
          (((size_t)ncg * 4 + kc) << 10) + (hf << 9) + (l31 << 4));
      f16x8 q0, q1;
      XFRAG(q0, Q + ((size_t)((mb << 8) + (wm << 6) + l31)) * QDIM +
                (kc << 4) + (hf << 3));
      XFRAG(q1, Q + ((size_t)((mb << 8) + (wm << 6) + 32 + l31)) * QDIM +
                (kc << 4) + (hf << 3));
      acc0 = __builtin_amdgcn_mfma_f32_32x32x16_f16(q0, bf, acc0, 0, 0, 0);
      acc1 = __builtin_amdgcn_mfma_f32_32x32x16_f16(q1, bf, acc1, 0, 0, 0);
    }
  }

  // epilogue: store to stripe ks. C/D (32x32): col = lane&31,
  // row = (reg&3) + 8*(reg>>2) + 4*(lane>>5)
  float* Pg = P + ((size_t)ks << 20);
  const int colg = (nc << 6) + (wn << 5) + l31;
  const int rbase = (mb << 8) + (wm << 6);
#pragma unroll
  for (int r = 0; r < 16; ++r) {
    const int rr = (r & 3) + ((r >> 2) << 3) + (hf << 2);
    Pg[(size_t)(rbase + rr) * 256 + colg] = acc0[r];
    Pg[(size_t)(rbase + 32 + rr) * 256 + colg] = acc1[r];
  }
}

// sum 8 fp32 stripes -> out. 1024 blocks x 256 threads x float4.
__global__ __launch_bounds__(256) void reduce8(const float* __restrict__ P,
                                               float* __restrict__ out) {
  const size_t i = (((size_t)blockIdx.x << 8) + threadIdx.x) << 2;
  float4 s = *(const float4*)(P + i);
#pragma unroll
  for (int g = 1; g < 8; ++g) {
    float4 v = *(const float4*)(P + ((size_t)g << 20) + i);
    s.x += v.x; s.y += v.y; s.z += v.z; s.w += v.w;
  }
  *(float4*)(out + i) = s;
}

extern "C" void kernel_launch(void* const* d_in, const int* in_sizes, int n_in,
                              void* d_out, int out_size, void* d_ws, size_t ws_size,
                              hipStream_t stream) {
  (void)in_sizes; (void)n_in; (void)out_size; (void)ws_size;
  const float* x  = (const float*)d_in[0];   // [4096,256]
  const float* q  = (const float*)d_in[1];   // [4096,64]
  const float* W1 = (const float*)d_in[2];   // [64,256,256]
  const float* b1 = (const float*)d_in[3];   // [64,256]
  float* out = (float*)d_out;                // [4096,256] fp32

  // ws: Wt 8 MB | Bt 32 KB | Xt 2 MB | P 8 x 4 MB = 32 MB  (~42 MB total)
  f16* Wt = (f16*)d_ws;
  f16* Bt = (f16*)((char*)d_ws + ((size_t)8 << 20));
  f16* Xt = (f16*)((char*)d_ws + ((size_t)8 << 20) + 32768);
  float* P = (float*)((char*)d_ws + ((size_t)8 << 20) + 32768 + ((size_t)2 << 20));

  prep<<<2113, 256, 0, stream>>>(W1, b1, x, Wt, Xt, Bt);
  mlp_main<<<512, 512, 0, stream>>>(q, Wt, Xt, Bt, P);
  reduce8<<<1024, 256, 0, stream>>>(P, out);
}